// Round 19
// baseline (310.867 us; speedup 1.0000x reference)
//
#include <hip/hip_runtime.h>
#include <math.h>

#define NN 2048
#define KNbr 16
#define BNpts 16384
#define BNKr  262144

__device__ __forceinline__ float eluf(float v) { return v > 0.f ? v : expm1f(v); }

// ---------------- KNN: ONE WAVE PER QUERY, f64-min key selection. -----------
// Round-18 selection + lane-local (lm, lm2) cache:
//   lm  = min of this lane's 32 live keys; lm2 = min excluding lm's slot
//   (slot recoverable from lm's payload: s = lo32(lm) >> 6).
// Per round: butterfly over lm only (6 fmin). On consumption the owner sets
// lm = lm2 (valid: lm2 excludes exactly the removed slot). A lane owning a
// SECOND winner triggers a wave-voted masked full-tree refill over kreg
// (cleared slots already INF). Invariant "lm == min(live keys)" holds at
// every butterfly => identical winner sequence, bit-identical output.
// Cost: +~10 VGPR (cache scalars), -55% f64-min ops vs full rescan.
__global__ __launch_bounds__(256) void knn_kernel(const float* __restrict__ pos,
                                                  int* __restrict__ idxout,
                                                  float* __restrict__ drel) {
  int wav = threadIdx.x >> 6, lane = threadIdx.x & 63;
  int bn = blockIdx.x*4 + wav;
  int b = bn >> 11, n = bn & (NN - 1);
  const float* pb = pos + (size_t)b * NN * 3;
  float qx = pb[n*3], qy = pb[n*3+1], qz = pb[n*3+2];
  float sqn = __fadd_rn(__fadd_rn(__fmul_rn(qx,qx), __fmul_rn(qy,qy)), __fmul_rn(qz,qz));
  double kreg[32];
#pragma unroll
  for (int s = 0; s < 32; ++s) {
    int m = s*64 + lane;
    float px = pb[m*3], py = pb[m*3+1], pz = pb[m*3+2];
    float sqm = __fadd_rn(__fadd_rn(__fmul_rn(px,px), __fmul_rn(py,py)), __fmul_rn(pz,pz));
    float dot = __fmaf_rn(qz, pz, __fmaf_rn(qy, py, __fmul_rn(qx, px)));
    float d2  = __fsub_rn(__fadd_rn(sqn, sqm), __fmul_rn(2.0f, dot));
    unsigned int bits = __float_as_uint(d2);
    unsigned int uf = bits ^ (((unsigned int)((int)bits >> 31)) >> 1);
    kreg[s] = __hiloint2double((int)uf, m);
  }
  const double KINF = __hiloint2double(0x7FF00000, 0);
#define TREE31(OUT) { \
    double g0 = fmin(fmin(kreg[0],  kreg[1]),  fmin(kreg[2],  kreg[3])); \
    double g1 = fmin(fmin(kreg[4],  kreg[5]),  fmin(kreg[6],  kreg[7])); \
    double g2 = fmin(fmin(kreg[8],  kreg[9]),  fmin(kreg[10], kreg[11])); \
    double g3 = fmin(fmin(kreg[12], kreg[13]), fmin(kreg[14], kreg[15])); \
    double g4 = fmin(fmin(kreg[16], kreg[17]), fmin(kreg[18], kreg[19])); \
    double g5 = fmin(fmin(kreg[20], kreg[21]), fmin(kreg[22], kreg[23])); \
    double g6 = fmin(fmin(kreg[24], kreg[25]), fmin(kreg[26], kreg[27])); \
    double g7 = fmin(fmin(kreg[28], kreg[29]), fmin(kreg[30], kreg[31])); \
    OUT = fmin(fmin(fmin(g0, g1), fmin(g2, g3)), \
               fmin(fmin(g4, g5), fmin(g6, g7))); }
  double lm, lm2;
  TREE31(lm)
  {
    int s1 = ((int)__double2loint(lm)) >> 6;   // this lane's argmin slot
#define LEAF(i) ((i) == s1 ? KINF : kreg[i])
    double g0 = fmin(fmin(LEAF(0),  LEAF(1)),  fmin(LEAF(2),  LEAF(3)));
    double g1 = fmin(fmin(LEAF(4),  LEAF(5)),  fmin(LEAF(6),  LEAF(7)));
    double g2 = fmin(fmin(LEAF(8),  LEAF(9)),  fmin(LEAF(10), LEAF(11)));
    double g3 = fmin(fmin(LEAF(12), LEAF(13)), fmin(LEAF(14), LEAF(15)));
    double g4 = fmin(fmin(LEAF(16), LEAF(17)), fmin(LEAF(18), LEAF(19)));
    double g5 = fmin(fmin(LEAF(20), LEAF(21)), fmin(LEAF(22), LEAF(23)));
    double g6 = fmin(fmin(LEAF(24), LEAF(25)), fmin(LEAF(26), LEAF(27)));
    double g7 = fmin(fmin(LEAF(28), LEAF(29)), fmin(LEAF(30), LEAF(31)));
    lm2 = fmin(fmin(fmin(g0, g1), fmin(g2, g3)),
               fmin(fmin(g4, g5), fmin(g6, g7)));
#undef LEAF
  }
  bool have2 = true;
  for (int k = 0; k < KNbr; ++k) {
    double bk = lm;
#pragma unroll
    for (int off = 32; off > 0; off >>= 1) {
      double ok = __shfl_xor(bk, off);
      bk = fmin(bk, ok);
    }
    int fi = __builtin_amdgcn_readfirstlane(__double2loint(bk));
    if (lane == 0) {
      idxout[bn*KNbr + k] = fi;
      drel[(size_t)(bn*KNbr + k)*3 + 0] = __fsub_rn(qx, pb[fi*3+0]);
      drel[(size_t)(bn*KNbr + k)*3 + 1] = __fsub_rn(qy, pb[fi*3+1]);
      drel[(size_t)(bn*KNbr + k)*3 + 2] = __fsub_rn(qz, pb[fi*3+2]);
    }
    bool owner = (lane == (fi & 63));
#define CLR(i) case i: if (owner) kreg[i] = KINF; break;
    switch (fi >> 6) {
      CLR(0)  CLR(1)  CLR(2)  CLR(3)  CLR(4)  CLR(5)  CLR(6)  CLR(7)
      CLR(8)  CLR(9)  CLR(10) CLR(11) CLR(12) CLR(13) CLR(14) CLR(15)
      CLR(16) CLR(17) CLR(18) CLR(19) CLR(20) CLR(21) CLR(22) CLR(23)
      CLR(24) CLR(25) CLR(26) CLR(27) CLR(28) CLR(29) CLR(30) CLR(31)
    }
#undef CLR
    bool need = false;
    if (owner) {
      if (have2) { lm = lm2; have2 = false; }
      else need = true;
    }
    if (__any(need)) {
      double nm;
      TREE31(nm)
      if (need) lm = nm;
    }
  }
#undef TREE31
}

// ---------------- mlp1 layer-1 stats: 1024 blocks x 1 row/thread ------------
__global__ __launch_bounds__(256) void s1a_kernel(const float* __restrict__ drel,
                                                  const float* __restrict__ W1,
                                                  const float* __restrict__ b1,
                                                  double* __restrict__ part1) {
  __shared__ float sW[64];
  int tid = threadIdx.x;
  if (tid < 48) sW[tid] = W1[tid];
  if (tid < 16) sW[48+tid] = b1[tid];
  __syncthreads();
  const float* src = drel + (size_t)(blockIdx.x*256 + tid)*3;
  float a0 = src[0], a1 = src[1], a2 = src[2];
  float s[16], s2[16];
#pragma unroll
  for (int c = 0; c < 16; ++c) {
    float v = a0*sW[c] + a1*sW[16+c] + a2*sW[32+c] + sW[48+c];
    float e = eluf(v);
    s[c] = e; s2[c] = e*e;
  }
  __shared__ float wred[4][32];
  int lane = tid & 63, wav = tid >> 6;
#pragma unroll
  for (int j = 0; j < 32; ++j) {
    float v = (j < 16) ? s[j] : s2[j-16];
    for (int sh = 32; sh > 0; sh >>= 1) v += __shfl_down(v, sh);
    if (lane == 0) wred[wav][j] = v;
  }
  __syncthreads();
  if (tid < 32)
    part1[(size_t)blockIdx.x*32 + tid] =
      (double)wred[0][tid] + (double)wred[1][tid] + (double)wred[2][tid] + (double)wred[3][tid];
}

// ---------------- bn over 16-ch partials [1024][32] -> sc/sh (f32) ----------
__global__ __launch_bounds__(256) void bn16_kernel(const double* __restrict__ part,
                                                   const float* __restrict__ g,
                                                   const float* __restrict__ be,
                                                   float* __restrict__ outp) {
  __shared__ double red[8][32];
  int t = threadIdx.x;
  int j = t & 31, grp = t >> 5;
  double v = 0.0;
#pragma unroll 4
  for (int bk = grp; bk < 1024; bk += 8) v += part[(size_t)bk*32 + j];
  red[grp][j] = v;
  __syncthreads();
  if (t < 32) {
    double s = 0.0;
    for (int gq = 0; gq < 8; ++gq) s += red[gq][t];
    red[0][t] = s;
  }
  __syncthreads();
  if (t < 16) {
    double S = red[0][t], S2 = red[0][16 + t];
    double m = S/262144.0, var = S2/262144.0 - m*m;
    double sc = (double)g[t]/sqrt(var + 1e-5);
    outp[t]      = (float)sc;
    outp[16 + t] = (float)((double)be[t] - m*sc);
  }
}

// ---------------- mlp1 layer-2 stats: 1024 blocks; bn1 precomputed ----------
__global__ __launch_bounds__(256) void s1b_kernel(const float* __restrict__ drel,
                                                  const float* __restrict__ W1,
                                                  const float* __restrict__ b1,
                                                  const float* __restrict__ W2,
                                                  const float* __restrict__ b2,
                                                  const float* __restrict__ bn1p,
                                                  double* __restrict__ part2) {
  int tid = threadIdx.x;
  __shared__ float fsc1[16], fsh1[16];
  __shared__ float sW[64];
  __shared__ float sW2t[256];
  if (tid < 16) { fsc1[tid] = bn1p[tid]; fsh1[tid] = bn1p[16 + tid]; }
  if (tid < 48) sW[tid] = W1[tid];
  if (tid < 16) sW[48+tid] = b1[tid];
  sW2t[tid] = W2[(tid & 15)*16 + (tid >> 4)];   // sW2t[c2*16+j] = W2[j][c2]
  __syncthreads();
  const float* src = drel + (size_t)(blockIdx.x*256 + tid)*3;
  float a0 = src[0], a1 = src[1], a2 = src[2];
  float s[16], s2[16];
  float y[16];
#pragma unroll
  for (int c = 0; c < 16; ++c) {
    float v = a0*sW[c] + a1*sW[16+c] + a2*sW[32+c] + sW[48+c];
    y[c] = eluf(v)*fsc1[c] + fsh1[c];
  }
#pragma unroll
  for (int c2 = 0; c2 < 16; ++c2) {
    float v = b2[c2];
    const float4* w4 = (const float4*)&sW2t[c2*16];
#pragma unroll
    for (int j4 = 0; j4 < 4; ++j4) {
      float4 ww = w4[j4];
      v += y[j4*4]*ww.x + y[j4*4+1]*ww.y + y[j4*4+2]*ww.z + y[j4*4+3]*ww.w;
    }
    float e = eluf(v);
    s[c2] = e; s2[c2] = e*e;
  }
  __shared__ float wred[4][32];
  int lane = tid & 63, wav = tid >> 6;
#pragma unroll
  for (int j = 0; j < 32; ++j) {
    float v = (j < 16) ? s[j] : s2[j-16];
    for (int sh = 32; sh > 0; sh >>= 1) v += __shfl_down(v, sh);
    if (lane == 0) wred[wav][j] = v;
  }
  __syncthreads();
  if (tid < 32)
    part2[(size_t)blockIdx.x*32 + tid] =
      (double)wred[0][tid] + (double)wred[1][tid] + (double)wred[2][tid] + (double)wred[3][tid];
}

// ---------------- mlp2 linear: 1024 blocks x 16 rows ------------------------
__global__ __launch_bounds__(256) void s2l_kernel(const float* __restrict__ drel,
                                                  const float* __restrict__ Wl,
                                                  const float* __restrict__ bl,
                                                  float* __restrict__ tL,
                                                  double* __restrict__ partL) {
  __shared__ float srows[16*48];
  int tid = threadIdx.x;
  const float* src = drel + (size_t)blockIdx.x * 768;
  for (int i = tid; i < 768; i += 256) srows[i] = src[i];
  float w[48];
#pragma unroll
  for (int j = 0; j < 48; ++j) w[j] = Wl[j*256 + tid];
  float bias = bl[tid];
  __syncthreads();
  double s = 0.0, s2 = 0.0;
  for (int r = 0; r < 16; ++r) {
    float v = bias;
    const float4* sr = (const float4*)&srows[r*48];
#pragma unroll
    for (int j4 = 0; j4 < 12; ++j4) {
      float4 a4 = sr[j4];
      v += a4.x*w[j4*4] + a4.y*w[j4*4+1] + a4.z*w[j4*4+2] + a4.w*w[j4*4+3];
    }
    float e = eluf(v);
    tL[(size_t)(blockIdx.x*16 + r)*256 + tid] = e;
    double ed = (double)e;
    s += ed; s2 += ed*ed;
  }
  partL[(size_t)blockIdx.x*512 + tid]       = s;
  partL[(size_t)blockIdx.x*512 + 256 + tid] = s2;
}

// ---------------- pre-reduce: part[1024][512] -> partS[256][512] ------------
__global__ __launch_bounds__(256) void pre512_kernel(const double* __restrict__ part,
                                                     double* __restrict__ partS) {
  int t = threadIdx.x;
  const double* p = part + (size_t)blockIdx.x*4*512;
  double a0 = 0.0, a1 = 0.0;
#pragma unroll
  for (int r = 0; r < 4; ++r) {
    a0 += p[r*512 + t];
    a1 += p[r*512 + 256 + t];
  }
  partS[(size_t)blockIdx.x*512 + t]       = a0;
  partS[(size_t)blockIdx.x*512 + 256 + t] = a1;
}

// ---------------- BN reduce: partS[256][512] -> sc/sh (f32) -----------------
__global__ __launch_bounds__(1024) void bnred_kernel(const double* __restrict__ part,
                                                     const float* __restrict__ g,
                                                     const float* __restrict__ be,
                                                     float* __restrict__ bnp) {
  __shared__ double red[1024];
  int t = threadIdx.x;
  int c = t & 255, half = (t >> 8) & 1, q = t >> 9;
  const double* p = part + (size_t)(q*128)*512 + half*256 + c;
  double v = 0.0;
#pragma unroll 4
  for (int bk = 0; bk < 128; ++bk) v += p[(size_t)bk*512];
  red[t] = v;
  __syncthreads();
  if (t < 256) {
    double S  = red[t]       + red[512 + t];
    double S2 = red[256 + t] + red[768 + t];
    double m = S/16384.0, var = S2/16384.0 - m*m;
    double sc = (double)g[t]/sqrt(var + 1e-5);
    bnp[t]       = (float)sc;
    bnp[256 + t] = (float)((double)be[t] - m*sc);
  }
}

// ---------------- grouped conv, IN-PLACE, 1024 blocks x 16 rows -------------
template<int DO_ELU>
__global__ __launch_bounds__(256) void s2conv_kernel(const float* __restrict__ bnIn,
                                                     const float* __restrict__ Wc,
                                                     const float* __restrict__ bc,
                                                     float* __restrict__ tBuf,
                                                     double* __restrict__ partOut) {
  int tid = threadIdx.x;
  float sc = bnIn[tid], sh = bnIn[256 + tid];
  int g = tid >> 4, o = tid & 15;
  float w[16];
#pragma unroll
  for (int k = 0; k < 16; ++k) w[k] = Wc[g*256 + o*16 + k];
  float bias = bc[tid];
  __shared__ float sin_[16*256];
  float* buf = tBuf + (size_t)blockIdx.x*16*256;
  for (int rr = 0; rr < 16; ++rr)
    sin_[rr*256 + tid] = buf[rr*256 + tid]*sc + sh;
  __syncthreads();
  double s = 0.0, s2 = 0.0;
  for (int rr = 0; rr < 16; ++rr) {
    float v = bias;
    const float4* row4 = (const float4*)&sin_[rr*256 + g*16];
#pragma unroll
    for (int k4 = 0; k4 < 4; ++k4) {
      float4 a4 = row4[k4];
      v += a4.x*w[k4*4] + a4.y*w[k4*4+1] + a4.z*w[k4*4+2] + a4.w*w[k4*4+3];
    }
    float e = DO_ELU ? eluf(v) : v;
    buf[rr*256 + tid] = e;
    double ed = (double)e;
    s += ed; s2 += ed*ed;
  }
  partOut[(size_t)blockIdx.x*512 + tid]       = s;
  partOut[(size_t)blockIdx.x*512 + 256 + tid] = s2;
}

// ---------------- final1: 4 pts/block; ov written to global -----------------
__global__ __launch_bounds__(256) void final1_kernel(const float* __restrict__ x,
                                                     const int* __restrict__ idxbuf,
                                                     const float* __restrict__ drel,
                                                     const float* __restrict__ tB,
                                                     const float* __restrict__ bnp,
                                                     const float* __restrict__ W1,
                                                     const float* __restrict__ b1,
                                                     const float* __restrict__ W2,
                                                     const float* __restrict__ b2,
                                                     const float* __restrict__ Wd,
                                                     const float* __restrict__ bd,
                                                     float* __restrict__ ovbuf) {
  int tid = threadIdx.x;
  int bn0 = blockIdx.x*4;
  int b = bn0 >> 11;
  __shared__ float sbn1[32], sbn2[32];
  __shared__ float sBs[256], sBh[256];
  __shared__ int   sidx[64];
  __shared__ float sdrel[192];
  __shared__ float sW1[48], sb1[16], sb2[16];
  __shared__ float sW2t[256];
  __shared__ float tmat[1024];
  __shared__ float hs[4][16][17];
  __shared__ float xst[4][16][80];    // [pt][k][c]
  if (tid < 32) { sbn1[tid] = bnp[tid]; sbn2[tid] = bnp[32 + tid]; }
  sBs[tid] = bnp[64 + tid];
  sBh[tid] = bnp[320 + tid];
  if (tid < 64) sidx[tid] = idxbuf[bn0*16 + tid];
  if (tid < 192) sdrel[tid] = drel[(size_t)bn0*48 + tid];
  if (tid < 48) sW1[tid] = W1[tid];
  if (tid < 16) { sb1[tid] = b1[tid]; sb2[tid] = b2[tid]; }
  sW2t[tid] = W2[(tid & 15)*16 + (tid >> 4)];
  __syncthreads();
  for (int i = tid; i < 1024; i += 256) {
    int c = i & 255;
    tmat[i] = tB[(size_t)bn0*256 + i]*sBs[c] + sBh[c];
  }
  for (int i = tid; i < 1024; i += 256) {
    int pt = i >> 8, k = (i >> 4) & 15, c = i & 15;
    float a0 = sdrel[pt*48 + k*3], a1 = sdrel[pt*48 + k*3 + 1], a2 = sdrel[pt*48 + k*3 + 2];
    float v = a0*sW1[c] + a1*sW1[16+c] + a2*sW1[32+c] + sb1[c];
    hs[pt][k][c] = eluf(v)*sbn1[c] + sbn1[16+c];
  }
  __syncthreads();
  for (int i = tid; i < 1024; i += 256) {
    int pt = i >> 8, k = (i >> 4) & 15, c2 = i & 15;
    float v = sb2[c2];
    const float4* w4 = (const float4*)&sW2t[c2*16];
    float* hrow = &hs[pt][k][0];
#pragma unroll
    for (int j4 = 0; j4 < 4; ++j4) {
      float4 ww = w4[j4];
      v += hrow[j4*4]*ww.x + hrow[j4*4+1]*ww.y + hrow[j4*4+2]*ww.z + hrow[j4*4+3]*ww.w;
    }
    xst[pt][k][c2] = eluf(v)*sbn2[c2] + sbn2[16+c2];
  }
  for (int i = tid; i < 1024; i += 256) {
    int pt = i >> 8, k = (i >> 4) & 15, c4 = i & 15;
    float4 xv = *(const float4*)&x[((size_t)b*NN + sidx[pt*16 + k])*64 + c4*4];
    *(float4*)&xst[pt][k][16 + c4*4] = xv;
  }
  __syncthreads();
  if (tid < 160) {
    int pt = (tid >= 80) ? 1 : 0;
    int c = tid - pt*80;
    float xtr0[16], xtr1[16];
#pragma unroll
    for (int o = 0; o < 16; ++o) { xtr0[o] = 0.f; xtr1[o] = 0.f; }
#pragma unroll
    for (int k = 0; k < 16; ++k) {
      float xv0 = xst[pt][k][c];
      float xv1 = xst[pt + 2][k][c];
      const float* tm0 = &tmat[pt*256 + k*16];
      const float* tm1 = &tmat[(pt + 2)*256 + k*16];
#pragma unroll
      for (int o = 0; o < 16; ++o) {
        xtr0[o] += xv0*tm0[o];
        xtr1[o] += xv1*tm1[o];
      }
    }
    float b0 = bd[c*2], b1v = bd[c*2 + 1];
    float v00 = b0, v01 = b1v, v10 = b0, v11 = b1v;
#pragma unroll
    for (int k = 0; k < 16; ++k) {
      float w0 = Wd[c*32 + k], w1 = Wd[c*32 + 16 + k];
      v00 += xtr0[k]*w0; v01 += xtr0[k]*w1;
      v10 += xtr1[k]*w0; v11 += xtr1[k]*w1;
    }
    ovbuf[(size_t)(bn0 + pt)*160 + c*2]       = v00;
    ovbuf[(size_t)(bn0 + pt)*160 + c*2 + 1]   = v01;
    ovbuf[(size_t)(bn0 + pt + 2)*160 + c*2]     = v10;
    ovbuf[(size_t)(bn0 + pt + 2)*160 + c*2 + 1] = v11;
  }
}

// ---------------- final2: tiled GEMM out = ov @ Wo + bo ---------------------
__global__ __launch_bounds__(256) void final2_kernel(const float* __restrict__ ovbuf,
                                                     const float* __restrict__ Wo,
                                                     const float* __restrict__ bo,
                                                     float* __restrict__ out) {
  __shared__ float ovt[32][164];
  int tid = threadIdx.x;
  int p0 = blockIdx.x*32;
  const float* src = ovbuf + (size_t)p0*160;
  for (int idx = tid; idx < 5120; idx += 256) {
    int p = idx / 160;
    int i = idx - p*160;
    ovt[p][i] = src[idx];
  }
  __syncthreads();
  int co = tid & 127, ph = tid >> 7;
  float bv = bo[co];
  float accs[16];
#pragma unroll
  for (int q = 0; q < 16; ++q) accs[q] = bv;
  for (int i4 = 0; i4 < 40; ++i4) {
    int i = i4*4;
    float w0 = Wo[i*128 + co];
    float w1 = Wo[(i+1)*128 + co];
    float w2 = Wo[(i+2)*128 + co];
    float w3 = Wo[(i+3)*128 + co];
#pragma unroll
    for (int q = 0; q < 16; ++q) {
      const float4 a = *(const float4*)&ovt[ph*16 + q][i];
      float acc = accs[q];
      acc += a.x*w0; acc += a.y*w1; acc += a.z*w2; acc += a.w*w3;
      accs[q] = acc;
    }
  }
#pragma unroll
  for (int q = 0; q < 16; ++q)
    out[(size_t)(p0 + ph*16 + q)*128 + co] = accs[q];
}

extern "C" void kernel_launch(void* const* d_in, const int* in_sizes, int n_in,
                              void* d_out, int out_size, void* d_ws, size_t ws_size,
                              hipStream_t stream) {
  (void)in_sizes; (void)n_in; (void)out_size; (void)ws_size;
  const float* x   = (const float*)d_in[0];
  const float* pos = (const float*)d_in[1];
  const float* W1  = (const float*)d_in[2];
  const float* b1  = (const float*)d_in[3];
  const float* g1  = (const float*)d_in[4];
  const float* be1 = (const float*)d_in[5];
  const float* W2  = (const float*)d_in[6];
  const float* b2  = (const float*)d_in[7];
  const float* g2  = (const float*)d_in[8];
  const float* be2 = (const float*)d_in[9];
  const float* Wl  = (const float*)d_in[10];
  const float* bl  = (const float*)d_in[11];
  const float* gl  = (const float*)d_in[12];
  const float* bel = (const float*)d_in[13];
  const float* WcA = (const float*)d_in[14];
  const float* bcA = (const float*)d_in[15];
  const float* gA  = (const float*)d_in[16];
  const float* beA = (const float*)d_in[17];
  const float* WcB = (const float*)d_in[18];
  const float* bcB = (const float*)d_in[19];
  const float* gB  = (const float*)d_in[20];
  const float* beB = (const float*)d_in[21];
  const float* Wd  = (const float*)d_in[22];
  const float* bd  = (const float*)d_in[23];
  const float* Wo  = (const float*)d_in[24];
  const float* bo  = (const float*)d_in[25];
  float* out = (float*)d_out;

  char* ws = (char*)d_ws;
  int*    idxbuf = (int*)ws;                                  // 1 MB
  float*  drel   = (float*)(ws + (1u<<20));                   // 3 MB
  float*  bufX   = (float*)(ws + (4u<<20));                   // 16 MB
  double* part1  = (double*)(ws + (20u<<20));                 // 256 KB (1024x32)
  double* part2  = (double*)(ws + (20u<<20) + (256u<<10));    // 256 KB
  double* P      = (double*)(ws + (20u<<20) + (512u<<10));    // 4 MB (1024x512)
  double* S      = (double*)(ws + (24u<<20) + (512u<<10));    // 1 MB (256x512)
  float*  bnp    = (float*)(ws + (25u<<20) + (512u<<10));     // 2.3 KB
  float*  bnpL   = (float*)(ws + (25u<<20) + (512u<<10) + 4096);  // 2 KB
  float*  bnpA   = (float*)(ws + (25u<<20) + (512u<<10) + 8192);  // 2 KB
  float*  ovbuf  = (float*)(ws + (26u<<20));                  // 10.5 MB (16384x160)

  knn_kernel<<<dim3(4096), dim3(256), 0, stream>>>(pos, idxbuf, drel);
  s1a_kernel<<<dim3(1024), dim3(256), 0, stream>>>(drel, W1, b1, part1);
  bn16_kernel<<<dim3(1), dim3(256), 0, stream>>>(part1, g1, be1, bnp + 0);
  s1b_kernel<<<dim3(1024), dim3(256), 0, stream>>>(drel, W1, b1, W2, b2, bnp + 0, part2);
  bn16_kernel<<<dim3(1), dim3(256), 0, stream>>>(part2, g2, be2, bnp + 32);
  s2l_kernel<<<dim3(1024), dim3(256), 0, stream>>>(drel, Wl, bl, bufX, P);
  pre512_kernel<<<dim3(256), dim3(256), 0, stream>>>(P, S);
  bnred_kernel<<<dim3(1), dim3(1024), 0, stream>>>(S, gl, bel, bnpL);
  s2conv_kernel<1><<<dim3(1024), dim3(256), 0, stream>>>(bnpL, WcA, bcA, bufX, P);
  pre512_kernel<<<dim3(256), dim3(256), 0, stream>>>(P, S);
  bnred_kernel<<<dim3(1), dim3(1024), 0, stream>>>(S, gA, beA, bnpA);
  s2conv_kernel<0><<<dim3(1024), dim3(256), 0, stream>>>(bnpA, WcB, bcB, bufX, P);
  pre512_kernel<<<dim3(256), dim3(256), 0, stream>>>(P, S);
  bnred_kernel<<<dim3(1), dim3(1024), 0, stream>>>(S, gB, beB, bnp + 64);
  final1_kernel<<<dim3(4096), dim3(256), 0, stream>>>(x, idxbuf, drel, bufX, bnp,
                                                      W1, b1, W2, b2, Wd, bd, ovbuf);
  final2_kernel<<<dim3(512), dim3(256), 0, stream>>>(ovbuf, Wo, bo, out);
}

// Round 20
// 298.115 us; speedup vs baseline: 1.0428x; 1.0428x over previous
//
#include <hip/hip_runtime.h>
#include <math.h>

#define NN 2048
#define KNbr 16
#define BNpts 16384
#define BNKr  262144

__device__ __forceinline__ float eluf(float v) { return v > 0.f ? v : expm1f(v); }

// ---------------- KNN: ONE WAVE PER QUERY, f64-min key selection. -----------
// (round-13/15/18 validated version — byte-identical. Rounds 14 & 19 both
// confirmed: any added live registers (pair-cache or lm/lm2 cache) drops
// occupancy below the latency-hiding floor and REGRESSES. Do not touch.)
__global__ __launch_bounds__(256) void knn_kernel(const float* __restrict__ pos,
                                                  int* __restrict__ idxout,
                                                  float* __restrict__ drel) {
  int wav = threadIdx.x >> 6, lane = threadIdx.x & 63;
  int bn = blockIdx.x*4 + wav;
  int b = bn >> 11, n = bn & (NN - 1);
  const float* pb = pos + (size_t)b * NN * 3;
  float qx = pb[n*3], qy = pb[n*3+1], qz = pb[n*3+2];
  float sqn = __fadd_rn(__fadd_rn(__fmul_rn(qx,qx), __fmul_rn(qy,qy)), __fmul_rn(qz,qz));
  double kreg[32];
#pragma unroll
  for (int s = 0; s < 32; ++s) {
    int m = s*64 + lane;
    float px = pb[m*3], py = pb[m*3+1], pz = pb[m*3+2];
    float sqm = __fadd_rn(__fadd_rn(__fmul_rn(px,px), __fmul_rn(py,py)), __fmul_rn(pz,pz));
    float dot = __fmaf_rn(qz, pz, __fmaf_rn(qy, py, __fmul_rn(qx, px)));
    float d2  = __fsub_rn(__fadd_rn(sqn, sqm), __fmul_rn(2.0f, dot));
    unsigned int bits = __float_as_uint(d2);
    unsigned int uf = bits ^ (((unsigned int)((int)bits >> 31)) >> 1);
    kreg[s] = __hiloint2double((int)uf, m);
  }
  const double KINF = __hiloint2double(0x7FF00000, 0);
  for (int k = 0; k < KNbr; ++k) {
    double g0 = fmin(fmin(kreg[0],  kreg[1]),  fmin(kreg[2],  kreg[3]));
    double g1 = fmin(fmin(kreg[4],  kreg[5]),  fmin(kreg[6],  kreg[7]));
    double g2 = fmin(fmin(kreg[8],  kreg[9]),  fmin(kreg[10], kreg[11]));
    double g3 = fmin(fmin(kreg[12], kreg[13]), fmin(kreg[14], kreg[15]));
    double g4 = fmin(fmin(kreg[16], kreg[17]), fmin(kreg[18], kreg[19]));
    double g5 = fmin(fmin(kreg[20], kreg[21]), fmin(kreg[22], kreg[23]));
    double g6 = fmin(fmin(kreg[24], kreg[25]), fmin(kreg[26], kreg[27]));
    double g7 = fmin(fmin(kreg[28], kreg[29]), fmin(kreg[30], kreg[31]));
    double bk = fmin(fmin(fmin(g0, g1), fmin(g2, g3)),
                     fmin(fmin(g4, g5), fmin(g6, g7)));
#pragma unroll
    for (int off = 32; off > 0; off >>= 1) {
      double ok = __shfl_xor(bk, off);
      bk = fmin(bk, ok);
    }
    int fi = __builtin_amdgcn_readfirstlane(__double2loint(bk));
    if (lane == 0) {
      idxout[bn*KNbr + k] = fi;
      drel[(size_t)(bn*KNbr + k)*3 + 0] = __fsub_rn(qx, pb[fi*3+0]);
      drel[(size_t)(bn*KNbr + k)*3 + 1] = __fsub_rn(qy, pb[fi*3+1]);
      drel[(size_t)(bn*KNbr + k)*3 + 2] = __fsub_rn(qz, pb[fi*3+2]);
    }
    bool owner = (lane == (fi & 63));
#define CLR(i) case i: if (owner) kreg[i] = KINF; break;
    switch (fi >> 6) {
      CLR(0)  CLR(1)  CLR(2)  CLR(3)  CLR(4)  CLR(5)  CLR(6)  CLR(7)
      CLR(8)  CLR(9)  CLR(10) CLR(11) CLR(12) CLR(13) CLR(14) CLR(15)
      CLR(16) CLR(17) CLR(18) CLR(19) CLR(20) CLR(21) CLR(22) CLR(23)
      CLR(24) CLR(25) CLR(26) CLR(27) CLR(28) CLR(29) CLR(30) CLR(31)
    }
#undef CLR
  }
}

// ---------------- mlp1 layer-1 stats: 1024 blocks x 1 row/thread ------------
__global__ __launch_bounds__(256) void s1a_kernel(const float* __restrict__ drel,
                                                  const float* __restrict__ W1,
                                                  const float* __restrict__ b1,
                                                  double* __restrict__ part1) {
  __shared__ float sW[64];
  int tid = threadIdx.x;
  if (tid < 48) sW[tid] = W1[tid];
  if (tid < 16) sW[48+tid] = b1[tid];
  __syncthreads();
  const float* src = drel + (size_t)(blockIdx.x*256 + tid)*3;
  float a0 = src[0], a1 = src[1], a2 = src[2];
  float s[16], s2[16];
#pragma unroll
  for (int c = 0; c < 16; ++c) {
    float v = a0*sW[c] + a1*sW[16+c] + a2*sW[32+c] + sW[48+c];
    float e = eluf(v);
    s[c] = e; s2[c] = e*e;
  }
  __shared__ float wred[4][32];
  int lane = tid & 63, wav = tid >> 6;
#pragma unroll
  for (int j = 0; j < 32; ++j) {
    float v = (j < 16) ? s[j] : s2[j-16];
    for (int sh = 32; sh > 0; sh >>= 1) v += __shfl_down(v, sh);
    if (lane == 0) wred[wav][j] = v;
  }
  __syncthreads();
  if (tid < 32)
    part1[(size_t)blockIdx.x*32 + tid] =
      (double)wred[0][tid] + (double)wred[1][tid] + (double)wred[2][tid] + (double)wred[3][tid];
}

// ---------------- bn over 16-ch partials [1024][32] -> sc/sh (f32) ----------
__global__ __launch_bounds__(256) void bn16_kernel(const double* __restrict__ part,
                                                   const float* __restrict__ g,
                                                   const float* __restrict__ be,
                                                   float* __restrict__ outp) {
  __shared__ double red[8][32];
  int t = threadIdx.x;
  int j = t & 31, grp = t >> 5;
  double v = 0.0;
#pragma unroll 4
  for (int bk = grp; bk < 1024; bk += 8) v += part[(size_t)bk*32 + j];
  red[grp][j] = v;
  __syncthreads();
  if (t < 32) {
    double s = 0.0;
    for (int gq = 0; gq < 8; ++gq) s += red[gq][t];
    red[0][t] = s;
  }
  __syncthreads();
  if (t < 16) {
    double S = red[0][t], S2 = red[0][16 + t];
    double m = S/262144.0, var = S2/262144.0 - m*m;
    double sc = (double)g[t]/sqrt(var + 1e-5);
    outp[t]      = (float)sc;
    outp[16 + t] = (float)((double)be[t] - m*sc);
  }
}

// ---------------- mlp1 layer-2 stats: 1024 blocks; bn1 precomputed ----------
__global__ __launch_bounds__(256) void s1b_kernel(const float* __restrict__ drel,
                                                  const float* __restrict__ W1,
                                                  const float* __restrict__ b1,
                                                  const float* __restrict__ W2,
                                                  const float* __restrict__ b2,
                                                  const float* __restrict__ bn1p,
                                                  double* __restrict__ part2) {
  int tid = threadIdx.x;
  __shared__ float fsc1[16], fsh1[16];
  __shared__ float sW[64];
  __shared__ float sW2t[256];
  if (tid < 16) { fsc1[tid] = bn1p[tid]; fsh1[tid] = bn1p[16 + tid]; }
  if (tid < 48) sW[tid] = W1[tid];
  if (tid < 16) sW[48+tid] = b1[tid];
  sW2t[tid] = W2[(tid & 15)*16 + (tid >> 4)];   // sW2t[c2*16+j] = W2[j][c2]
  __syncthreads();
  const float* src = drel + (size_t)(blockIdx.x*256 + tid)*3;
  float a0 = src[0], a1 = src[1], a2 = src[2];
  float s[16], s2[16];
  float y[16];
#pragma unroll
  for (int c = 0; c < 16; ++c) {
    float v = a0*sW[c] + a1*sW[16+c] + a2*sW[32+c] + sW[48+c];
    y[c] = eluf(v)*fsc1[c] + fsh1[c];
  }
#pragma unroll
  for (int c2 = 0; c2 < 16; ++c2) {
    float v = b2[c2];
    const float4* w4 = (const float4*)&sW2t[c2*16];
#pragma unroll
    for (int j4 = 0; j4 < 4; ++j4) {
      float4 ww = w4[j4];
      v += y[j4*4]*ww.x + y[j4*4+1]*ww.y + y[j4*4+2]*ww.z + y[j4*4+3]*ww.w;
    }
    float e = eluf(v);
    s[c2] = e; s2[c2] = e*e;
  }
  __shared__ float wred[4][32];
  int lane = tid & 63, wav = tid >> 6;
#pragma unroll
  for (int j = 0; j < 32; ++j) {
    float v = (j < 16) ? s[j] : s2[j-16];
    for (int sh = 32; sh > 0; sh >>= 1) v += __shfl_down(v, sh);
    if (lane == 0) wred[wav][j] = v;
  }
  __syncthreads();
  if (tid < 32)
    part2[(size_t)blockIdx.x*32 + tid] =
      (double)wred[0][tid] + (double)wred[1][tid] + (double)wred[2][tid] + (double)wred[3][tid];
}

// ---------------- mlp2 linear: 1024 blocks x 16 rows ------------------------
__global__ __launch_bounds__(256) void s2l_kernel(const float* __restrict__ drel,
                                                  const float* __restrict__ Wl,
                                                  const float* __restrict__ bl,
                                                  float* __restrict__ tL,
                                                  double* __restrict__ partL) {
  __shared__ float srows[16*48];
  int tid = threadIdx.x;
  const float* src = drel + (size_t)blockIdx.x * 768;
  for (int i = tid; i < 768; i += 256) srows[i] = src[i];
  float w[48];
#pragma unroll
  for (int j = 0; j < 48; ++j) w[j] = Wl[j*256 + tid];
  float bias = bl[tid];
  __syncthreads();
  double s = 0.0, s2 = 0.0;
  for (int r = 0; r < 16; ++r) {
    float v = bias;
    const float4* sr = (const float4*)&srows[r*48];
#pragma unroll
    for (int j4 = 0; j4 < 12; ++j4) {
      float4 a4 = sr[j4];
      v += a4.x*w[j4*4] + a4.y*w[j4*4+1] + a4.z*w[j4*4+2] + a4.w*w[j4*4+3];
    }
    float e = eluf(v);
    tL[(size_t)(blockIdx.x*16 + r)*256 + tid] = e;
    double ed = (double)e;
    s += ed; s2 += ed*ed;
  }
  partL[(size_t)blockIdx.x*512 + tid]       = s;
  partL[(size_t)blockIdx.x*512 + 256 + tid] = s2;
}

// ---------------- pre-reduce: part[1024][512] -> partS[256][512] ------------
__global__ __launch_bounds__(256) void pre512_kernel(const double* __restrict__ part,
                                                     double* __restrict__ partS) {
  int t = threadIdx.x;
  const double* p = part + (size_t)blockIdx.x*4*512;
  double a0 = 0.0, a1 = 0.0;
#pragma unroll
  for (int r = 0; r < 4; ++r) {
    a0 += p[r*512 + t];
    a1 += p[r*512 + 256 + t];
  }
  partS[(size_t)blockIdx.x*512 + t]       = a0;
  partS[(size_t)blockIdx.x*512 + 256 + t] = a1;
}

// ---------------- BN reduce: partS[256][512] -> sc/sh (f32) -----------------
__global__ __launch_bounds__(1024) void bnred_kernel(const double* __restrict__ part,
                                                     const float* __restrict__ g,
                                                     const float* __restrict__ be,
                                                     float* __restrict__ bnp) {
  __shared__ double red[1024];
  int t = threadIdx.x;
  int c = t & 255, half = (t >> 8) & 1, q = t >> 9;
  const double* p = part + (size_t)(q*128)*512 + half*256 + c;
  double v = 0.0;
#pragma unroll 4
  for (int bk = 0; bk < 128; ++bk) v += p[(size_t)bk*512];
  red[t] = v;
  __syncthreads();
  if (t < 256) {
    double S  = red[t]       + red[512 + t];
    double S2 = red[256 + t] + red[768 + t];
    double m = S/16384.0, var = S2/16384.0 - m*m;
    double sc = (double)g[t]/sqrt(var + 1e-5);
    bnp[t]       = (float)sc;
    bnp[256 + t] = (float)((double)be[t] - m*sc);
  }
}

// ---------------- grouped conv, IN-PLACE, 1024 blocks x 16 rows -------------
template<int DO_ELU>
__global__ __launch_bounds__(256) void s2conv_kernel(const float* __restrict__ bnIn,
                                                     const float* __restrict__ Wc,
                                                     const float* __restrict__ bc,
                                                     float* __restrict__ tBuf,
                                                     double* __restrict__ partOut) {
  int tid = threadIdx.x;
  float sc = bnIn[tid], sh = bnIn[256 + tid];
  int g = tid >> 4, o = tid & 15;
  float w[16];
#pragma unroll
  for (int k = 0; k < 16; ++k) w[k] = Wc[g*256 + o*16 + k];
  float bias = bc[tid];
  __shared__ float sin_[16*256];
  float* buf = tBuf + (size_t)blockIdx.x*16*256;
  for (int rr = 0; rr < 16; ++rr)
    sin_[rr*256 + tid] = buf[rr*256 + tid]*sc + sh;
  __syncthreads();
  double s = 0.0, s2 = 0.0;
  for (int rr = 0; rr < 16; ++rr) {
    float v = bias;
    const float4* row4 = (const float4*)&sin_[rr*256 + g*16];
#pragma unroll
    for (int k4 = 0; k4 < 4; ++k4) {
      float4 a4 = row4[k4];
      v += a4.x*w[k4*4] + a4.y*w[k4*4+1] + a4.z*w[k4*4+2] + a4.w*w[k4*4+3];
    }
    float e = DO_ELU ? eluf(v) : v;
    buf[rr*256 + tid] = e;
    double ed = (double)e;
    s += ed; s2 += ed*ed;
  }
  partOut[(size_t)blockIdx.x*512 + tid]       = s;
  partOut[(size_t)blockIdx.x*512 + 256 + tid] = s2;
}

// ---------------- final1: 4 pts/block; ov written to global -----------------
__global__ __launch_bounds__(256) void final1_kernel(const float* __restrict__ x,
                                                     const int* __restrict__ idxbuf,
                                                     const float* __restrict__ drel,
                                                     const float* __restrict__ tB,
                                                     const float* __restrict__ bnp,
                                                     const float* __restrict__ W1,
                                                     const float* __restrict__ b1,
                                                     const float* __restrict__ W2,
                                                     const float* __restrict__ b2,
                                                     const float* __restrict__ Wd,
                                                     const float* __restrict__ bd,
                                                     float* __restrict__ ovbuf) {
  int tid = threadIdx.x;
  int bn0 = blockIdx.x*4;
  int b = bn0 >> 11;
  __shared__ float sbn1[32], sbn2[32];
  __shared__ float sBs[256], sBh[256];
  __shared__ int   sidx[64];
  __shared__ float sdrel[192];
  __shared__ float sW1[48], sb1[16], sb2[16];
  __shared__ float sW2t[256];
  __shared__ float tmat[1024];
  __shared__ float hs[4][16][17];
  __shared__ float xst[4][16][80];    // [pt][k][c]
  if (tid < 32) { sbn1[tid] = bnp[tid]; sbn2[tid] = bnp[32 + tid]; }
  sBs[tid] = bnp[64 + tid];
  sBh[tid] = bnp[320 + tid];
  if (tid < 64) sidx[tid] = idxbuf[bn0*16 + tid];
  if (tid < 192) sdrel[tid] = drel[(size_t)bn0*48 + tid];
  if (tid < 48) sW1[tid] = W1[tid];
  if (tid < 16) { sb1[tid] = b1[tid]; sb2[tid] = b2[tid]; }
  sW2t[tid] = W2[(tid & 15)*16 + (tid >> 4)];
  __syncthreads();
  for (int i = tid; i < 1024; i += 256) {
    int c = i & 255;
    tmat[i] = tB[(size_t)bn0*256 + i]*sBs[c] + sBh[c];
  }
  for (int i = tid; i < 1024; i += 256) {
    int pt = i >> 8, k = (i >> 4) & 15, c = i & 15;
    float a0 = sdrel[pt*48 + k*3], a1 = sdrel[pt*48 + k*3 + 1], a2 = sdrel[pt*48 + k*3 + 2];
    float v = a0*sW1[c] + a1*sW1[16+c] + a2*sW1[32+c] + sb1[c];
    hs[pt][k][c] = eluf(v)*sbn1[c] + sbn1[16+c];
  }
  __syncthreads();
  for (int i = tid; i < 1024; i += 256) {
    int pt = i >> 8, k = (i >> 4) & 15, c2 = i & 15;
    float v = sb2[c2];
    const float4* w4 = (const float4*)&sW2t[c2*16];
    float* hrow = &hs[pt][k][0];
#pragma unroll
    for (int j4 = 0; j4 < 4; ++j4) {
      float4 ww = w4[j4];
      v += hrow[j4*4]*ww.x + hrow[j4*4+1]*ww.y + hrow[j4*4+2]*ww.z + hrow[j4*4+3]*ww.w;
    }
    xst[pt][k][c2] = eluf(v)*sbn2[c2] + sbn2[16+c2];
  }
  for (int i = tid; i < 1024; i += 256) {
    int pt = i >> 8, k = (i >> 4) & 15, c4 = i & 15;
    float4 xv = *(const float4*)&x[((size_t)b*NN + sidx[pt*16 + k])*64 + c4*4];
    *(float4*)&xst[pt][k][16 + c4*4] = xv;
  }
  __syncthreads();
  if (tid < 160) {
    int pt = (tid >= 80) ? 1 : 0;
    int c = tid - pt*80;
    float xtr0[16], xtr1[16];
#pragma unroll
    for (int o = 0; o < 16; ++o) { xtr0[o] = 0.f; xtr1[o] = 0.f; }
#pragma unroll
    for (int k = 0; k < 16; ++k) {
      float xv0 = xst[pt][k][c];
      float xv1 = xst[pt + 2][k][c];
      const float* tm0 = &tmat[pt*256 + k*16];
      const float* tm1 = &tmat[(pt + 2)*256 + k*16];
#pragma unroll
      for (int o = 0; o < 16; ++o) {
        xtr0[o] += xv0*tm0[o];
        xtr1[o] += xv1*tm1[o];
      }
    }
    float b0 = bd[c*2], b1v = bd[c*2 + 1];
    float v00 = b0, v01 = b1v, v10 = b0, v11 = b1v;
#pragma unroll
    for (int k = 0; k < 16; ++k) {
      float w0 = Wd[c*32 + k], w1 = Wd[c*32 + 16 + k];
      v00 += xtr0[k]*w0; v01 += xtr0[k]*w1;
      v10 += xtr1[k]*w0; v11 += xtr1[k]*w1;
    }
    ovbuf[(size_t)(bn0 + pt)*160 + c*2]       = v00;
    ovbuf[(size_t)(bn0 + pt)*160 + c*2 + 1]   = v01;
    ovbuf[(size_t)(bn0 + pt + 2)*160 + c*2]     = v10;
    ovbuf[(size_t)(bn0 + pt + 2)*160 + c*2 + 1] = v11;
  }
}

// ---------------- final2: tiled GEMM out = ov @ Wo + bo ---------------------
__global__ __launch_bounds__(256) void final2_kernel(const float* __restrict__ ovbuf,
                                                     const float* __restrict__ Wo,
                                                     const float* __restrict__ bo,
                                                     float* __restrict__ out) {
  __shared__ float ovt[32][164];
  int tid = threadIdx.x;
  int p0 = blockIdx.x*32;
  const float* src = ovbuf + (size_t)p0*160;
  for (int idx = tid; idx < 5120; idx += 256) {
    int p = idx / 160;
    int i = idx - p*160;
    ovt[p][i] = src[idx];
  }
  __syncthreads();
  int co = tid & 127, ph = tid >> 7;
  float bv = bo[co];
  float accs[16];
#pragma unroll
  for (int q = 0; q < 16; ++q) accs[q] = bv;
  for (int i4 = 0; i4 < 40; ++i4) {
    int i = i4*4;
    float w0 = Wo[i*128 + co];
    float w1 = Wo[(i+1)*128 + co];
    float w2 = Wo[(i+2)*128 + co];
    float w3 = Wo[(i+3)*128 + co];
#pragma unroll
    for (int q = 0; q < 16; ++q) {
      const float4 a = *(const float4*)&ovt[ph*16 + q][i];
      float acc = accs[q];
      acc += a.x*w0; acc += a.y*w1; acc += a.z*w2; acc += a.w*w3;
      accs[q] = acc;
    }
  }
#pragma unroll
  for (int q = 0; q < 16; ++q)
    out[(size_t)(p0 + ph*16 + q)*128 + co] = accs[q];
}

extern "C" void kernel_launch(void* const* d_in, const int* in_sizes, int n_in,
                              void* d_out, int out_size, void* d_ws, size_t ws_size,
                              hipStream_t stream) {
  (void)in_sizes; (void)n_in; (void)out_size; (void)ws_size;
  const float* x   = (const float*)d_in[0];
  const float* pos = (const float*)d_in[1];
  const float* W1  = (const float*)d_in[2];
  const float* b1  = (const float*)d_in[3];
  const float* g1  = (const float*)d_in[4];
  const float* be1 = (const float*)d_in[5];
  const float* W2  = (const float*)d_in[6];
  const float* b2  = (const float*)d_in[7];
  const float* g2  = (const float*)d_in[8];
  const float* be2 = (const float*)d_in[9];
  const float* Wl  = (const float*)d_in[10];
  const float* bl  = (const float*)d_in[11];
  const float* gl  = (const float*)d_in[12];
  const float* bel = (const float*)d_in[13];
  const float* WcA = (const float*)d_in[14];
  const float* bcA = (const float*)d_in[15];
  const float* gA  = (const float*)d_in[16];
  const float* beA = (const float*)d_in[17];
  const float* WcB = (const float*)d_in[18];
  const float* bcB = (const float*)d_in[19];
  const float* gB  = (const float*)d_in[20];
  const float* beB = (const float*)d_in[21];
  const float* Wd  = (const float*)d_in[22];
  const float* bd  = (const float*)d_in[23];
  const float* Wo  = (const float*)d_in[24];
  const float* bo  = (const float*)d_in[25];
  float* out = (float*)d_out;

  char* ws = (char*)d_ws;
  int*    idxbuf = (int*)ws;                                  // 1 MB
  float*  drel   = (float*)(ws + (1u<<20));                   // 3 MB
  float*  bufX   = (float*)(ws + (4u<<20));                   // 16 MB
  double* part1  = (double*)(ws + (20u<<20));                 // 256 KB (1024x32)
  double* part2  = (double*)(ws + (20u<<20) + (256u<<10));    // 256 KB
  double* P      = (double*)(ws + (20u<<20) + (512u<<10));    // 4 MB (1024x512)
  double* S      = (double*)(ws + (24u<<20) + (512u<<10));    // 1 MB (256x512)
  float*  bnp    = (float*)(ws + (25u<<20) + (512u<<10));     // 2.3 KB
  float*  bnpL   = (float*)(ws + (25u<<20) + (512u<<10) + 4096);  // 2 KB
  float*  bnpA   = (float*)(ws + (25u<<20) + (512u<<10) + 8192);  // 2 KB
  float*  ovbuf  = (float*)(ws + (26u<<20));                  // 10.5 MB (16384x160)

  knn_kernel<<<dim3(4096), dim3(256), 0, stream>>>(pos, idxbuf, drel);
  s1a_kernel<<<dim3(1024), dim3(256), 0, stream>>>(drel, W1, b1, part1);
  bn16_kernel<<<dim3(1), dim3(256), 0, stream>>>(part1, g1, be1, bnp + 0);
  s1b_kernel<<<dim3(1024), dim3(256), 0, stream>>>(drel, W1, b1, W2, b2, bnp + 0, part2);
  bn16_kernel<<<dim3(1), dim3(256), 0, stream>>>(part2, g2, be2, bnp + 32);
  s2l_kernel<<<dim3(1024), dim3(256), 0, stream>>>(drel, Wl, bl, bufX, P);
  pre512_kernel<<<dim3(256), dim3(256), 0, stream>>>(P, S);
  bnred_kernel<<<dim3(1), dim3(1024), 0, stream>>>(S, gl, bel, bnpL);
  s2conv_kernel<1><<<dim3(1024), dim3(256), 0, stream>>>(bnpL, WcA, bcA, bufX, P);
  pre512_kernel<<<dim3(256), dim3(256), 0, stream>>>(P, S);
  bnred_kernel<<<dim3(1), dim3(1024), 0, stream>>>(S, gA, beA, bnpA);
  s2conv_kernel<0><<<dim3(1024), dim3(256), 0, stream>>>(bnpA, WcB, bcB, bufX, P);
  pre512_kernel<<<dim3(256), dim3(256), 0, stream>>>(P, S);
  bnred_kernel<<<dim3(1), dim3(1024), 0, stream>>>(S, gB, beB, bnp + 64);
  final1_kernel<<<dim3(4096), dim3(256), 0, stream>>>(x, idxbuf, drel, bufX, bnp,
                                                      W1, b1, W2, b2, Wd, bd, ovbuf);
  final2_kernel<<<dim3(512), dim3(256), 0, stream>>>(ovbuf, Wo, bo, out);
}